// Round 4
// baseline (5393.566 us; speedup 1.0000x reference)
//
#include <hip/hip_runtime.h>
#include <float.h>

// MAM dense two-phase. C[m,n] = max_k(A[m,k]*W[n,k]) + min_k + bias[n], plus
// argmax/argmin (first occurrence).
//
// R3 lesson: single-pass cmp+cndmask index tracking = 7 generic VALU per
// product at ~4cy each (SIMD-16 rate for non-FMA VALU) = 1.5 ms ceiling.
// Split: phase 1 computes ONLY values via max3/min3 (~2 instr/product);
// phase 2 recovers indices via wave-wide equality ballots (1 mul + 2 v_cmp
// per product, index resolution in SALU which co-issues under VALU).
// Match is bitwise-exact (same v_mul_f32 in both phases); ties resolve to
// lowest k (s_ff1 + ascending chunks) = numpy first-occurrence semantics.

#define BM 64
#define BN 64
#define BK 32
#define LDP (BM + 4)

__global__ __launch_bounds__(256)
void mam_phase1(const float* __restrict__ A, const float* __restrict__ W,
                const float* __restrict__ bias,
                float* __restrict__ out_v, float* __restrict__ out_ax,
                float* __restrict__ out_an, int M, int N, int K) {
  __shared__ __align__(16) float Als[BK][LDP];
  __shared__ __align__(16) float Wls[BK][LDP];

  const int tid = threadIdx.x;
  const int tx = tid & 15;
  const int ty = tid >> 4;
  const int m0 = blockIdx.y * BM;
  const int n0 = blockIdx.x * BN;

  float vmax[4][4], vmin[4][4];
#pragma unroll
  for (int i = 0; i < 4; ++i)
#pragma unroll
    for (int j = 0; j < 4; ++j) {
      vmax[i][j] = -FLT_MAX;
      vmin[i][j] = FLT_MAX;
    }

  const int r = tid >> 3;  // 0..31
  const int c = tid & 7;   // 0..7

  for (int kk = 0; kk < K; kk += BK) {
#pragma unroll
    for (int rr = 0; rr < 2; ++rr) {
      const int row = r + rr * 32;
      int gm = m0 + row; gm = gm < M ? gm : M - 1;
      const float4 va = *(const float4*)(A + (size_t)gm * K + kk + c * 4);
      Als[c * 4 + 0][row] = va.x;
      Als[c * 4 + 1][row] = va.y;
      Als[c * 4 + 2][row] = va.z;
      Als[c * 4 + 3][row] = va.w;
      int gn = n0 + row; gn = gn < N ? gn : N - 1;
      const float4 vw = *(const float4*)(W + (size_t)gn * K + kk + c * 4);
      Wls[c * 4 + 0][row] = vw.x;
      Wls[c * 4 + 1][row] = vw.y;
      Wls[c * 4 + 2][row] = vw.z;
      Wls[c * 4 + 3][row] = vw.w;
    }
    __syncthreads();

#pragma unroll
    for (int k = 0; k < BK; k += 2) {
      const float4 av0 = *(const float4*)(&Als[k][ty * 4]);
      const float4 av1 = *(const float4*)(&Als[k + 1][ty * 4]);
      const float4 wv0 = *(const float4*)(&Wls[k][tx * 4]);
      const float4 wv1 = *(const float4*)(&Wls[k + 1][tx * 4]);
      const float a0[4] = {av0.x, av0.y, av0.z, av0.w};
      const float a1[4] = {av1.x, av1.y, av1.z, av1.w};
      const float w0[4] = {wv0.x, wv0.y, wv0.z, wv0.w};
      const float w1[4] = {wv1.x, wv1.y, wv1.z, wv1.w};
#pragma unroll
      for (int i = 0; i < 4; ++i)
#pragma unroll
        for (int j = 0; j < 4; ++j) {
          const float p0 = a0[i] * w0[j];
          const float p1 = a1[i] * w1[j];
          vmax[i][j] = fmaxf(vmax[i][j], fmaxf(p0, p1));  // -> v_max3_f32
          vmin[i][j] = fminf(vmin[i][j], fminf(p0, p1));  // -> v_min3_f32
        }
    }
    __syncthreads();
  }

  const int gn = n0 + tx * 4;
  float4 bv = make_float4(0.f, 0.f, 0.f, 0.f);
  if (gn + 3 < N) bv = *(const float4*)(bias + gn);
#pragma unroll
  for (int i = 0; i < 4; ++i) {
    const int gm = m0 + ty * 4 + i;
    if (gm < M && gn + 3 < N) {
      const size_t base = (size_t)gm * N + gn;
      float4 o;
      o.x = vmax[i][0] + vmin[i][0] + bv.x;
      o.y = vmax[i][1] + vmin[i][1] + bv.y;
      o.z = vmax[i][2] + vmin[i][2] + bv.z;
      o.w = vmax[i][3] + vmin[i][3] + bv.w;
      *(float4*)(out_v + base) = o;
      // park raw targets for phase 2 (overwritten with indices there)
      *(float4*)(out_ax + base) =
          make_float4(vmax[i][0], vmax[i][1], vmax[i][2], vmax[i][3]);
      *(float4*)(out_an + base) =
          make_float4(vmin[i][0], vmin[i][1], vmin[i][2], vmin[i][3]);
    }
  }
}

// ---------------- Phase 2: index recovery via ballots ----------------
// Block: 16 n-cols x 256 m-rows; 4 waves, each owns 64 m-rows.
// W rows for the block staged fully (16 x K floats = 64 KB LDS), one barrier.
// A read from global (L1/L2 resident). Per 4x4 output group, scan K in
// 64-wide chunks (lane <-> k). Per product: v_mul + 2 v_cmp_eq (ballot);
// index resolution is uniform SALU guarded by `if (mask)` (rare-taken).

#define P2NB 16
#define P2MB 256

__global__ __launch_bounds__(256)
void mam_phase2(const float* __restrict__ A, const float* __restrict__ W,
                float* out_ax, float* out_an, int M, int N, int K) {
  __shared__ float Wls[P2NB * 1024];  // K assumed <= 1024 (here exactly 1024)

  const int tid = threadIdx.x;
  const int n0 = blockIdx.x * P2NB;

  // stage W[n0..n0+16) x K
  {
    const int row = tid >> 4;  // 0..15
    const int cg = tid & 15;   // 0..15
    const float* wr = W + (size_t)(n0 + row) * K;
#pragma unroll
    for (int rep = 0; rep < 16; ++rep) {  // 16 float4 per thread (K=1024)
      const int c4 = cg + rep * 16;
      const float4 v = *(const float4*)(wr + c4 * 4);
      *(float4*)(&Wls[row * 1024 + c4 * 4]) = v;
    }
  }
  __syncthreads();

  const int lane = tid & 63;
  const int wv = __builtin_amdgcn_readfirstlane(tid >> 6);
  const int mwave = blockIdx.y * P2MB + wv * 64;

  for (int mg = 0; mg < 16; ++mg) {
    const int m0 = mwave + mg * 4;
    const float* ar0 = A + (size_t)(m0 + 0) * K + lane;
    const float* ar1 = A + (size_t)(m0 + 1) * K + lane;
    const float* ar2 = A + (size_t)(m0 + 2) * K + lane;
    const float* ar3 = A + (size_t)(m0 + 3) * K + lane;

    for (int ng = 0; ng < 4; ++ng) {
      const int nl0 = ng * 4;
      const int gn0 = n0 + nl0;
      // targets (uniform addresses -> broadcast loads)
      float tx[4][4], tn[4][4];
#pragma unroll
      for (int i = 0; i < 4; ++i)
#pragma unroll
        for (int j = 0; j < 4; ++j) {
          const size_t o = (size_t)(m0 + i) * N + gn0 + j;
          tx[i][j] = out_ax[o];
          tn[i][j] = out_an[o];
        }
      unsigned cx[4][4], cn[4][4];
#pragma unroll
      for (int i = 0; i < 4; ++i)
#pragma unroll
        for (int j = 0; j < 4; ++j) { cx[i][j] = 0xFFFFFFFFu; cn[i][j] = 0xFFFFFFFFu; }

      const int wbase = nl0 * 1024 + lane;

#pragma unroll 4
      for (int ck = 0; ck < 16; ++ck) {
        const int kk = ck * 64;
        const float a[4] = {ar0[kk], ar1[kk], ar2[kk], ar3[kk]};
        const float w[4] = {Wls[wbase + 0 * 1024 + kk], Wls[wbase + 1 * 1024 + kk],
                            Wls[wbase + 2 * 1024 + kk], Wls[wbase + 3 * 1024 + kk]};
#pragma unroll
        for (int i = 0; i < 4; ++i) {
          // batch ballots per row, then resolve (keeps v_cmps pipelined)
          unsigned long long mx[4], mn[4];
#pragma unroll
          for (int j = 0; j < 4; ++j) {
            const float p = a[i] * w[j];
            mx[j] = __ballot(p == tx[i][j]);
            mn[j] = __ballot(p == tn[i][j]);
          }
#pragma unroll
          for (int j = 0; j < 4; ++j) {
            // readfirstlane insurance: force uniform/SALU domain
            unsigned long long mmx =
                ((unsigned long long)__builtin_amdgcn_readfirstlane((unsigned)(mx[j] >> 32)) << 32) |
                __builtin_amdgcn_readfirstlane((unsigned)mx[j]);
            if (mmx) {
              const unsigned cand = (unsigned)kk + (unsigned)__builtin_ctzll(mmx);
              if (cand < cx[i][j]) cx[i][j] = cand;
            }
            unsigned long long mmn =
                ((unsigned long long)__builtin_amdgcn_readfirstlane((unsigned)(mn[j] >> 32)) << 32) |
                __builtin_amdgcn_readfirstlane((unsigned)mn[j]);
            if (mmn) {
              const unsigned cand = (unsigned)kk + (unsigned)__builtin_ctzll(mmn);
              if (cand < cn[i][j]) cn[i][j] = cand;
            }
          }
        }
      }

      if (lane == 0) {
#pragma unroll
        for (int i = 0; i < 4; ++i)
#pragma unroll
          for (int j = 0; j < 4; ++j) {
            const size_t o = (size_t)(m0 + i) * N + gn0 + j;
            out_ax[o] = (float)cx[i][j];
            out_an[o] = (float)cn[i][j];
          }
      }
    }
  }
}

extern "C" void kernel_launch(void* const* d_in, const int* in_sizes, int n_in,
                              void* d_out, int out_size, void* d_ws, size_t ws_size,
                              hipStream_t stream) {
  const float* A = (const float*)d_in[0];     // [M, K] fp32
  const float* W = (const float*)d_in[1];     // [N, K] fp32
  const float* bias = (const float*)d_in[2];  // [N]    fp32
  const int N = in_sizes[2];
  const int K = in_sizes[1] / N;
  const int M = in_sizes[0] / K;
  float* out_v = (float*)d_out;
  float* out_ax = out_v + (size_t)M * N;
  float* out_an = out_v + 2 * (size_t)M * N;

  dim3 grid1((N + BN - 1) / BN, (M + BM - 1) / BM);
  mam_phase1<<<grid1, dim3(256), 0, stream>>>(A, W, bias, out_v, out_ax, out_an,
                                              M, N, K);
  dim3 grid2(N / P2NB, M / P2MB);
  mam_phase2<<<grid2, dim3(256), 0, stream>>>(A, W, out_ax, out_an, M, N, K);
}

// Round 5
// 1017.120 us; speedup vs baseline: 5.3028x; 5.3028x over previous
//
#include <hip/hip_runtime.h>
#include <float.h>

// MAM dense, fused single kernel.
// C[m,n] = max_k(A[m,k]*W[n,k]) + min_k + bias[n], plus argmax/argmin
// (numpy first-occurrence semantics).
//
// Calibrated model (R3/R4): v_mul ~2cy, generic VALU (cmp/cndmask/max3) ~4cy
// per wave instr. Inline (val,idx) tracking = 7 ops/product = 1.5 ms ceiling
// (R3). Value-only via max3/min3 = 2 ops/product (~540 us, R4 phase 1).
// This kernel adds CHUNK tracking (BK=32 window where running max/min last
// changed, +0.19 ops/product) and recovers the in-chunk position in an
// epilogue: entries bucketed by (chunk,side) via LDS atomics (no per-lane
// chunk divergence — R4's ballot/SALU resolution was SALU-bound at 16%
// VALUBusy), then per chunk: re-stage 32-k slice, scan entries
// thread-parallel with strict >/< (keeps first occurrence).
// Last-changed-chunk + first-in-chunk-match == global first occurrence:
// running max reaches its final value exactly in the chunk containing the
// first global occurrence, and never changes after (strict > merge).

#define BM 64
#define BN 64
#define BK 32
#define LDP (BM + 4)
#define NCHUNK 32              // K / BK for K=1024
#define NBUCKET (2 * NCHUNK)   // (chunk, side)
#define NENT (BM * BN * 2)     // 8192

__global__ __launch_bounds__(256)
void mam_fused(const float* __restrict__ A, const float* __restrict__ W,
               const float* __restrict__ bias,
               float* __restrict__ out_v, float* __restrict__ out_ax,
               float* __restrict__ out_an, int M, int N, int K) {
  __shared__ __align__(16) float Als[BK][LDP];
  __shared__ __align__(16) float Wls[BK][LDP];
  __shared__ unsigned short ents[NENT];
  __shared__ unsigned cnt[NBUCKET];
  __shared__ unsigned off[NBUCKET + 1];

  const int tid = threadIdx.x;
  const int tx = tid & 15;
  const int ty = tid >> 4;
  const int m0 = blockIdx.y * BM;
  const int n0 = blockIdx.x * BN;

  float vmax[4][4], vmin[4][4];
  int cmax[4][4], cmin[4][4];
#pragma unroll
  for (int i = 0; i < 4; ++i)
#pragma unroll
    for (int j = 0; j < 4; ++j) {
      vmax[i][j] = -FLT_MAX;
      vmin[i][j] = FLT_MAX;
      cmax[i][j] = 0;
      cmin[i][j] = 0;
    }

  const int r = tid >> 3;  // 0..31
  const int c8 = tid & 7;  // 0..7

  const int nchunk = K / BK;
  for (int ch = 0; ch < nchunk; ++ch) {
    const int kk = ch * BK;
    // ---- stage chunk into transposed LDS [k][row] ----
#pragma unroll
    for (int rr = 0; rr < 2; ++rr) {
      const int row = r + rr * 32;
      int gm = m0 + row; gm = gm < M ? gm : M - 1;
      const float4 va = *(const float4*)(A + (size_t)gm * K + kk + c8 * 4);
      Als[c8 * 4 + 0][row] = va.x;
      Als[c8 * 4 + 1][row] = va.y;
      Als[c8 * 4 + 2][row] = va.z;
      Als[c8 * 4 + 3][row] = va.w;
      int gn = n0 + row; gn = gn < N ? gn : N - 1;
      const float4 vw = *(const float4*)(W + (size_t)gn * K + kk + c8 * 4);
      Wls[c8 * 4 + 0][row] = vw.x;
      Wls[c8 * 4 + 1][row] = vw.y;
      Wls[c8 * 4 + 2][row] = vw.z;
      Wls[c8 * 4 + 3][row] = vw.w;
    }
    __syncthreads();

    // ---- chunk-local max/min (values only, max3/min3) ----
    float tmax[4][4], tmin[4][4];
#pragma unroll
    for (int i = 0; i < 4; ++i)
#pragma unroll
      for (int j = 0; j < 4; ++j) { tmax[i][j] = -FLT_MAX; tmin[i][j] = FLT_MAX; }

#pragma unroll
    for (int k = 0; k < BK; k += 2) {
      const float4 av0 = *(const float4*)(&Als[k][ty * 4]);
      const float4 av1 = *(const float4*)(&Als[k + 1][ty * 4]);
      const float4 wv0 = *(const float4*)(&Wls[k][tx * 4]);
      const float4 wv1 = *(const float4*)(&Wls[k + 1][tx * 4]);
      const float a0[4] = {av0.x, av0.y, av0.z, av0.w};
      const float a1[4] = {av1.x, av1.y, av1.z, av1.w};
      const float w0[4] = {wv0.x, wv0.y, wv0.z, wv0.w};
      const float w1[4] = {wv1.x, wv1.y, wv1.z, wv1.w};
#pragma unroll
      for (int i = 0; i < 4; ++i)
#pragma unroll
        for (int j = 0; j < 4; ++j) {
          const float p0 = a0[i] * w0[j];
          const float p1 = a1[i] * w1[j];
          tmax[i][j] = fmaxf(tmax[i][j], fmaxf(p0, p1));  // v_max3_f32
          tmin[i][j] = fminf(tmin[i][j], fminf(p0, p1));  // v_min3_f32
        }
    }

    // ---- merge chunk into running (strict: first chunk wins on ties) ----
#pragma unroll
    for (int i = 0; i < 4; ++i)
#pragma unroll
      for (int j = 0; j < 4; ++j) {
        if (tmax[i][j] > vmax[i][j]) { vmax[i][j] = tmax[i][j]; cmax[i][j] = ch; }
        if (tmin[i][j] < vmin[i][j]) { vmin[i][j] = tmin[i][j]; cmin[i][j] = ch; }
      }
    __syncthreads();
  }

  // ---- value output ----
  const int gn = n0 + tx * 4;
  float4 bv = make_float4(0.f, 0.f, 0.f, 0.f);
  if (gn + 3 < N) bv = *(const float4*)(bias + gn);
#pragma unroll
  for (int i = 0; i < 4; ++i) {
    const int gm = m0 + ty * 4 + i;
    if (gm < M && gn + 3 < N) {
      const size_t base = (size_t)gm * N + gn;
      float4 o;
      o.x = vmax[i][0] + vmin[i][0] + bv.x;
      o.y = vmax[i][1] + vmin[i][1] + bv.y;
      o.z = vmax[i][2] + vmin[i][2] + bv.z;
      o.w = vmax[i][3] + vmin[i][3] + bv.w;
      *(float4*)(out_v + base) = o;
    }
  }

  // ---- bucket entries by (chunk, side) ----
  if (tid < NBUCKET) cnt[tid] = 0;
  __syncthreads();
#pragma unroll
  for (int i = 0; i < 4; ++i)
#pragma unroll
    for (int j = 0; j < 4; ++j) {
      atomicAdd(&cnt[2 * cmax[i][j] + 0], 1u);
      atomicAdd(&cnt[2 * cmin[i][j] + 1], 1u);
    }
  __syncthreads();
  if (tid == 0) {
    unsigned s = 0;
    for (int b = 0; b < NBUCKET; ++b) { off[b] = s; s += cnt[b]; }
    off[NBUCKET] = s;
  }
  __syncthreads();
  if (tid < NBUCKET) cnt[tid] = off[tid];  // cursors
  __syncthreads();
#pragma unroll
  for (int i = 0; i < 4; ++i)
#pragma unroll
    for (int j = 0; j < 4; ++j) {
      const unsigned enc = (unsigned)((ty * 4 + i) * 64 + (tx * 4 + j));
      unsigned p1 = atomicAdd(&cnt[2 * cmax[i][j] + 0], 1u);
      ents[p1] = (unsigned short)enc;
      unsigned p2 = atomicAdd(&cnt[2 * cmin[i][j] + 1], 1u);
      ents[p2] = (unsigned short)enc;
    }
  __syncthreads();

  // ---- per-chunk rescan: recover in-chunk first occurrence ----
  for (int ch = 0; ch < nchunk; ++ch) {
    const int kk = ch * BK;
    __syncthreads();  // previous scan readers done before overwrite
#pragma unroll
    for (int rr = 0; rr < 2; ++rr) {
      const int row = r + rr * 32;
      int gm = m0 + row; gm = gm < M ? gm : M - 1;
      const float4 va = *(const float4*)(A + (size_t)gm * K + kk + c8 * 4);
      Als[c8 * 4 + 0][row] = va.x;
      Als[c8 * 4 + 1][row] = va.y;
      Als[c8 * 4 + 2][row] = va.z;
      Als[c8 * 4 + 3][row] = va.w;
      int gnr = n0 + row; gnr = gnr < N ? gnr : N - 1;
      const float4 vw = *(const float4*)(W + (size_t)gnr * K + kk + c8 * 4);
      Wls[c8 * 4 + 0][row] = vw.x;
      Wls[c8 * 4 + 1][row] = vw.y;
      Wls[c8 * 4 + 2][row] = vw.z;
      Wls[c8 * 4 + 3][row] = vw.w;
    }
    __syncthreads();

    // max-side bucket (uniform side per loop -> no per-lane select)
    const int bmax_lo = off[2 * ch], bmax_hi = off[2 * ch + 1];
    for (int e = bmax_lo + tid; e < bmax_hi; e += 256) {
      const int enc = ents[e];
      const int ml = enc >> 6;
      const int nl = enc & 63;
      float best = -FLT_MAX;
      int pos = 0;
#pragma unroll
      for (int k = 0; k < BK; ++k) {
        const float p = Als[k][ml] * Wls[k][nl];
        if (p > best) { best = p; pos = k; }  // strict: first occurrence
      }
      const int gm = m0 + ml, gnn = n0 + nl;
      if (gm < M && gnn < N)
        out_ax[(size_t)gm * N + gnn] = (float)(kk + pos);
    }
    // min-side bucket
    const int bmin_lo = off[2 * ch + 1], bmin_hi = off[2 * ch + 2];
    for (int e = bmin_lo + tid; e < bmin_hi; e += 256) {
      const int enc = ents[e];
      const int ml = enc >> 6;
      const int nl = enc & 63;
      float best = FLT_MAX;
      int pos = 0;
#pragma unroll
      for (int k = 0; k < BK; ++k) {
        const float p = Als[k][ml] * Wls[k][nl];
        if (p < best) { best = p; pos = k; }
      }
      const int gm = m0 + ml, gnn = n0 + nl;
      if (gm < M && gnn < N)
        out_an[(size_t)gm * N + gnn] = (float)(kk + pos);
    }
  }
}

extern "C" void kernel_launch(void* const* d_in, const int* in_sizes, int n_in,
                              void* d_out, int out_size, void* d_ws, size_t ws_size,
                              hipStream_t stream) {
  const float* A = (const float*)d_in[0];     // [M, K] fp32
  const float* W = (const float*)d_in[1];     // [N, K] fp32
  const float* bias = (const float*)d_in[2];  // [N]    fp32
  const int N = in_sizes[2];
  const int K = in_sizes[1] / N;
  const int M = in_sizes[0] / K;
  float* out_v = (float*)d_out;
  float* out_ax = out_v + (size_t)M * N;
  float* out_an = out_v + 2 * (size_t)M * N;
  dim3 grid((N + BN - 1) / BN, (M + BM - 1) / BM);
  mam_fused<<<grid, dim3(256), 0, stream>>>(A, W, bias, out_v, out_ax, out_an,
                                            M, N, K);
}

// Round 9
// 920.719 us; speedup vs baseline: 5.8580x; 1.1047x over previous
//
#include <hip/hip_runtime.h>
#include <float.h>

// MAM dense, fused. C[m,n] = max_k(A[m,k]*W[n,k]) + min_k + bias[n] + arg
// indices (numpy first-occurrence).
//
//  - Main pass: 64x64 tile, 4x4/thread, values via max3/min3 (2 ops/product)
//    + chunk-of-last-change tracking (BK=32 windows, ~0.19 ops/product).
//  - Targets: fmax/fmin chains return an input BITWISE, so final vmax/vmin
//    equals one product in its winning chunk exactly. Park targets in LDS.
//  - Rescan: entries bucketed by chunk (LDS atomics + prefix). Per chunk:
//    re-stage the 32-k slice ROW-MAJOR [row][36] (144B stride: 16B-aligned
//    rows, rotating 4-bank windows tile all banks evenly for random-row
//    b128 gathers). Scan DESCENDING k with pos=(a*w==t)?k:pos — last write
//    wins = smallest k = first occurrence; 3 VALU/k, one path for both sides.
//
// R8 crash fix: pool must be sized for the LARGER aliased layout
// (rescan [64][36]x2 = 18432B, not main [32][68]x2 = 17408B). The R7 repost
// under-sized it; Ws2's last 1KB overwrote ents[0..511] -> corrupt side bits
// -> out-of-bounds global writes -> abort.

#define BM 64
#define BN 64
#define BK 32
#define LDP 68    // main staging [BK][LDP], +4 pad
#define LDP2 36   // rescan row-major [64][LDP2]; 144B stride
#define NCHUNK 32
#define NENT (BM * BN * 2)

__global__ __launch_bounds__(256)
void mam_fused(const float* __restrict__ A, const float* __restrict__ W,
               const float* __restrict__ bias,
               float* __restrict__ out_v, float* __restrict__ out_ax,
               float* __restrict__ out_an, int M, int N, int K) {
  // aliased staging pool, sized for the larger layout:
  //   main:   Als[32][68] @0 (8704B) + Wls[32][68] @8704 (ends 17408B)
  //   rescan: As2[64][36] @0 (9216B) + Ws2[64][36] @9216 (ends 18432B)
  __shared__ __align__(16) unsigned char pool[2 * 64 * LDP2 * 4];
  float(*Als)[LDP] = (float(*)[LDP])pool;
  float(*Wls)[LDP] = (float(*)[LDP])(pool + BK * LDP * 4);
  float(*As2)[LDP2] = (float(*)[LDP2])pool;
  float(*Ws2)[LDP2] = (float(*)[LDP2])(pool + 64 * LDP2 * 4);
  __shared__ unsigned short ents[NENT];
  __shared__ float tgt[8192];  // [side][ml*64+nl], 32 KB
  __shared__ unsigned cnt[NCHUNK];
  __shared__ unsigned off[NCHUNK + 1];

  const int tid = threadIdx.x;
  const int tx = tid & 15;
  const int ty = tid >> 4;
  const int m0 = blockIdx.y * BM;
  const int n0 = blockIdx.x * BN;

  float vmax[4][4], vmin[4][4];
  int cmax[4][4], cmin[4][4];
#pragma unroll
  for (int i = 0; i < 4; ++i)
#pragma unroll
    for (int j = 0; j < 4; ++j) {
      vmax[i][j] = -FLT_MAX;
      vmin[i][j] = FLT_MAX;
      cmax[i][j] = 0;
      cmin[i][j] = 0;
    }

  const int r = tid >> 3;  // 0..31
  const int c8 = tid & 7;  // 0..7

  const int nchunk = K / BK;
  for (int ch = 0; ch < nchunk; ++ch) {
    const int kk = ch * BK;
#pragma unroll
    for (int rr = 0; rr < 2; ++rr) {
      const int row = r + rr * 32;
      int gm = m0 + row; gm = gm < M ? gm : M - 1;
      const float4 va = *(const float4*)(A + (size_t)gm * K + kk + c8 * 4);
      Als[c8 * 4 + 0][row] = va.x;
      Als[c8 * 4 + 1][row] = va.y;
      Als[c8 * 4 + 2][row] = va.z;
      Als[c8 * 4 + 3][row] = va.w;
      int gn = n0 + row; gn = gn < N ? gn : N - 1;
      const float4 vw = *(const float4*)(W + (size_t)gn * K + kk + c8 * 4);
      Wls[c8 * 4 + 0][row] = vw.x;
      Wls[c8 * 4 + 1][row] = vw.y;
      Wls[c8 * 4 + 2][row] = vw.z;
      Wls[c8 * 4 + 3][row] = vw.w;
    }
    __syncthreads();

    float tmax[4][4], tmin[4][4];
#pragma unroll
    for (int i = 0; i < 4; ++i)
#pragma unroll
      for (int j = 0; j < 4; ++j) { tmax[i][j] = -FLT_MAX; tmin[i][j] = FLT_MAX; }

#pragma unroll
    for (int k = 0; k < BK; k += 2) {
      const float4 av0 = *(const float4*)(&Als[k][ty * 4]);
      const float4 av1 = *(const float4*)(&Als[k + 1][ty * 4]);
      const float4 wv0 = *(const float4*)(&Wls[k][tx * 4]);
      const float4 wv1 = *(const float4*)(&Wls[k + 1][tx * 4]);
      const float a0[4] = {av0.x, av0.y, av0.z, av0.w};
      const float a1[4] = {av1.x, av1.y, av1.z, av1.w};
      const float w0[4] = {wv0.x, wv0.y, wv0.z, wv0.w};
      const float w1[4] = {wv1.x, wv1.y, wv1.z, wv1.w};
#pragma unroll
      for (int i = 0; i < 4; ++i)
#pragma unroll
        for (int j = 0; j < 4; ++j) {
          const float p0 = a0[i] * w0[j];
          const float p1 = a1[i] * w1[j];
          tmax[i][j] = fmaxf(tmax[i][j], fmaxf(p0, p1));  // v_max3_f32
          tmin[i][j] = fminf(tmin[i][j], fminf(p0, p1));  // v_min3_f32
        }
    }

#pragma unroll
    for (int i = 0; i < 4; ++i)
#pragma unroll
      for (int j = 0; j < 4; ++j) {
        if (tmax[i][j] > vmax[i][j]) { vmax[i][j] = tmax[i][j]; cmax[i][j] = ch; }
        if (tmin[i][j] < vmin[i][j]) { vmin[i][j] = tmin[i][j]; cmin[i][j] = ch; }
      }
    __syncthreads();
  }

  // ---- value output + park targets in LDS ----
  const int gn = n0 + tx * 4;
  float4 bv = make_float4(0.f, 0.f, 0.f, 0.f);
  if (gn + 3 < N) bv = *(const float4*)(bias + gn);
#pragma unroll
  for (int i = 0; i < 4; ++i) {
    const int gm = m0 + ty * 4 + i;
    if (gm < M && gn + 3 < N) {
      const size_t base = (size_t)gm * N + gn;
      float4 o;
      o.x = vmax[i][0] + vmin[i][0] + bv.x;
      o.y = vmax[i][1] + vmin[i][1] + bv.y;
      o.z = vmax[i][2] + vmin[i][2] + bv.z;
      o.w = vmax[i][3] + vmin[i][3] + bv.w;
      *(float4*)(out_v + base) = o;
    }
#pragma unroll
    for (int j = 0; j < 4; ++j) {
      const int idx = (ty * 4 + i) * 64 + tx * 4 + j;
      tgt[idx] = vmax[i][j];         // side 0
      tgt[4096 + idx] = vmin[i][j];  // side 1
    }
  }

  // ---- bucket entries by chunk (side rides in the entry) ----
  if (tid < NCHUNK) cnt[tid] = 0;
  __syncthreads();
#pragma unroll
  for (int i = 0; i < 4; ++i)
#pragma unroll
    for (int j = 0; j < 4; ++j) {
      atomicAdd(&cnt[cmax[i][j]], 1u);
      atomicAdd(&cnt[cmin[i][j]], 1u);
    }
  __syncthreads();
  if (tid == 0) {
    unsigned s = 0;
    for (int b = 0; b < NCHUNK; ++b) { off[b] = s; s += cnt[b]; }
    off[NCHUNK] = s;
  }
  __syncthreads();
  if (tid < NCHUNK) cnt[tid] = off[tid];
  __syncthreads();
#pragma unroll
  for (int i = 0; i < 4; ++i)
#pragma unroll
    for (int j = 0; j < 4; ++j) {
      const unsigned enc = (unsigned)((ty * 4 + i) * 64 + (tx * 4 + j));
      unsigned p1 = atomicAdd(&cnt[cmax[i][j]], 1u);
      ents[p1] = (unsigned short)enc;               // side 0
      unsigned p2 = atomicAdd(&cnt[cmin[i][j]], 1u);
      ents[p2] = (unsigned short)(enc | 0x1000u);   // side 1
    }

  // ---- per-chunk rescan: first k with product == target ----
  const int row2 = tid >> 2;  // 0..63
  const int q2 = tid & 3;     // 0..3
  const size_t MN = (size_t)M * N;

  for (int ch = 0; ch < nchunk; ++ch) {
    const int kk = ch * BK;
    __syncthreads();  // prior readers (and bucketing/targets) done
    {
      int gm = m0 + row2; gm = gm < M ? gm : M - 1;
      const float* ar = A + (size_t)gm * K + kk;
      const float4 a0 = *(const float4*)(ar + q2 * 4);
      const float4 a1 = *(const float4*)(ar + q2 * 4 + 16);
      *(float4*)(&As2[row2][q2 * 4]) = a0;
      *(float4*)(&As2[row2][q2 * 4 + 16]) = a1;
      int gnr = n0 + row2; gnr = gnr < N ? gnr : N - 1;
      const float* wr = W + (size_t)gnr * K + kk;
      const float4 w0 = *(const float4*)(wr + q2 * 4);
      const float4 w1 = *(const float4*)(wr + q2 * 4 + 16);
      *(float4*)(&Ws2[row2][q2 * 4]) = w0;
      *(float4*)(&Ws2[row2][q2 * 4 + 16]) = w1;
    }
    __syncthreads();

    const int lo = off[ch], hi = off[ch + 1];
    for (int e = lo + tid; e < hi; e += 256) {
      const int enc = ents[e];
      const int side = enc >> 12;
      const int ml = (enc >> 6) & 63;
      const int nl = enc & 63;
      const float t = tgt[side * 4096 + (enc & 0xFFF)];
      unsigned pos = 0;
#pragma unroll
      for (int g = 7; g >= 0; --g) {  // descending k: last write = min k
        const float4 a4 = *(const float4*)(&As2[ml][g * 4]);
        const float4 w4 = *(const float4*)(&Ws2[nl][g * 4]);
        pos = (a4.w * w4.w == t) ? (unsigned)(g * 4 + 3) : pos;
        pos = (a4.z * w4.z == t) ? (unsigned)(g * 4 + 2) : pos;
        pos = (a4.y * w4.y == t) ? (unsigned)(g * 4 + 1) : pos;
        pos = (a4.x * w4.x == t) ? (unsigned)(g * 4 + 0) : pos;
      }
      const int gm = m0 + ml, gnn = n0 + nl;
      if (gm < M && gnn < N) {
        float* outp = out_ax + (size_t)side * MN;  // out_an = out_ax + MN
        outp[(size_t)gm * N + gnn] = (float)(kk + (int)pos);
      }
    }
  }
}

extern "C" void kernel_launch(void* const* d_in, const int* in_sizes, int n_in,
                              void* d_out, int out_size, void* d_ws, size_t ws_size,
                              hipStream_t stream) {
  const float* A = (const float*)d_in[0];     // [M, K] fp32
  const float* W = (const float*)d_in[1];     // [N, K] fp32
  const float* bias = (const float*)d_in[2];  // [N]    fp32
  const int N = in_sizes[2];
  const int K = in_sizes[1] / N;
  const int M = in_sizes[0] / K;
  float* out_v = (float*)d_out;
  float* out_ax = out_v + (size_t)M * N;
  float* out_an = out_v + 2 * (size_t)M * N;
  dim3 grid((N + BN - 1) / BN, (M + BM - 1) / BM);
  mam_fused<<<grid, dim3(256), 0, stream>>>(A, W, bias, out_v, out_ax, out_an,
                                            M, N, K);
}